// Round 3
// baseline (61.029 us; speedup 1.0000x reference)
//
#include <hip/hip_runtime.h>

constexpr int K = 3;
constexpr int BLK = 256;            // threads per block = pixels per block (one row segment)
constexpr int WIN_ROWS = 4;         // rows h-1 .. h+2
constexpr int WIN_COLS = BLK + 4;   // cols w0-1 .. w0+BLK+2  (kx in [-1,+1], +1 for x1)

__device__ __forceinline__ float corner_val(
    const float* __restrict__ img, const float* __restrict__ lds,
    int yi, int xi, int r0, int cw0, int H, int W)
{
    const int ry = yi - r0;
    const int rx = xi - cw0;
    if ((unsigned)ry < (unsigned)WIN_ROWS && (unsigned)rx < (unsigned)WIN_COLS) {
        return lds[ry * WIN_COLS + rx];       // window already zero-padded at image edges
    }
    // generic fallback (exec-masked out when all lanes hit the window)
    const bool valid = ((unsigned)yi < (unsigned)H) & ((unsigned)xi < (unsigned)W);
    return valid ? img[yi * W + xi] : 0.f;
}

__global__ __launch_bounds__(BLK, 6) void deform_conv2d_kernel(
    const float* __restrict__ inp,     // (B,H,W)
    const float* __restrict__ wgt,     // (K*K)
    const float* __restrict__ off,     // (B, 2*K*K, H, W)
    float* __restrict__ out,           // (B,H,W)
    int B, int H, int W)
{
    __shared__ float lds[WIN_ROWS * WIN_COLS];

    const int HW = H * W;
    const int wblocks = W / BLK;               // 2 for W=512
    const int bid = blockIdx.x;
    const int w0  = (bid % wblocks) * BLK;
    const int h   = (bid / wblocks) % H;
    const int b   = bid / (wblocks * H);
    const int t   = threadIdx.x;
    const int w   = w0 + t;
    const int hw  = h * W + w;

    const float* __restrict__ img  = inp + (size_t)b * HW;
    const float* __restrict__ offb = off + (size_t)b * (2 * K * K) * HW + hw;

    // 1) issue all 18 offset loads first (coalesced dwords; latency overlaps staging)
    float oy[K * K], ox[K * K];
#pragma unroll
    for (int k = 0; k < K * K; ++k) {
        oy[k] = offb[(size_t)(2 * k)     * HW];
        ox[k] = offb[(size_t)(2 * k + 1) * HW];
    }

    // 2) stage zero-padded 4 x 260 input window into LDS (coalesced within rows)
    const int r0  = h - 1;
    const int cw0 = w0 - 1;
    for (int c = t; c < WIN_ROWS * WIN_COLS; c += BLK) {
        const int ry = c / WIN_COLS;
        const int rx = c - ry * WIN_COLS;
        const int gy = r0 + ry;
        const int gx = cw0 + rx;
        float v = 0.f;
        if (((unsigned)gy < (unsigned)H) & ((unsigned)gx < (unsigned)W))
            v = img[gy * W + gx];
        lds[c] = v;
    }
    __syncthreads();

    // 3) bilinear taps from LDS
    float acc = 0.f;
#pragma unroll
    for (int k = 0; k < K * K; ++k) {
        const int ky = k / K - 1;
        const int kx = k % K - 1;

        const float y = (float)(h + ky) + oy[k];
        const float x = (float)(w + kx) + ox[k];

        const float y0f = floorf(y);
        const float x0f = floorf(x);
        const float ly = y - y0f, lx = x - x0f;
        const float hy = 1.f - ly, hx = 1.f - lx;

        const int y0 = (int)y0f, x0 = (int)x0f;

        const float v00 = corner_val(img, lds, y0,     x0,     r0, cw0, H, W);
        const float v01 = corner_val(img, lds, y0,     x0 + 1, r0, cw0, H, W);
        const float v10 = corner_val(img, lds, y0 + 1, x0,     r0, cw0, H, W);
        const float v11 = corner_val(img, lds, y0 + 1, x0 + 1, r0, cw0, H, W);

        acc += wgt[k] * (hy * hx * v00 + hy * lx * v01 + ly * hx * v10 + ly * lx * v11);
    }

    out[(size_t)b * HW + hw] = acc;
}

extern "C" void kernel_launch(void* const* d_in, const int* in_sizes, int n_in,
                              void* d_out, int out_size, void* d_ws, size_t ws_size,
                              hipStream_t stream)
{
    const float* inp = (const float*)d_in[0];   // (8,512,512)
    const float* wgt = (const float*)d_in[1];   // (1,1,3,3) = 9 floats
    const float* off = (const float*)d_in[2];   // (8,18,512,512)
    float* out = (float*)d_out;

    const int B = 8, H = 512, W = 512;
    const int grid = 8 * 512 * (512 / BLK);     // one block per 256-px row segment

    deform_conv2d_kernel<<<grid, BLK, 0, stream>>>(inp, wgt, off, out, B, H, W);
}

// Round 4
// 39.952 us; speedup vs baseline: 1.5276x; 1.5276x over previous
//
#include <hip/hip_runtime.h>

constexpr int K  = 3;
constexpr int Hc = 512, Wc = 512, Bc = 8;
constexpr int HWc = Hc * Wc;

#if __has_builtin(__builtin_amdgcn_make_buffer_rsrc) && __has_builtin(__builtin_amdgcn_raw_buffer_load_b32)
#define USE_BUF 1
#else
#define USE_BUF 0
#endif

__global__ __launch_bounds__(256, 6) void deform_conv2d_kernel(
    const float* __restrict__ inp,     // (B,H,W)
    const float* __restrict__ wgt,     // (K*K)
    const float* __restrict__ off,     // (B, 2*K*K, H, W)
    float* __restrict__ out)           // (B,H,W)
{
    const int p  = blockIdx.x * blockDim.x + threadIdx.x;   // one pixel per thread
    const int b  = p >> 18;            // / (512*512)
    const int hw = p & (HWc - 1);
    const int h  = hw >> 9;            // / 512  (wave-uniform: blocks never span rows)
    const int w  = hw & (Wc - 1);

    const float* __restrict__ img  = inp + (size_t)b * HWc;
    const float* __restrict__ offb = off + (size_t)b * (2 * K * K) * HWc + hw;

    // Issue all 18 offset loads up-front (independent, fully coalesced dwords).
    float oy[K * K], ox[K * K];
#pragma unroll
    for (int k = 0; k < K * K; ++k) {
        oy[k] = offb[(2 * k)     * HWc];
        ox[k] = offb[(2 * k + 1) * HWc];
    }

#if USE_BUF
    // SRSRC over this batch's image plane: HW bounds check zeroes any tap whose
    // flat index falls outside [0, H*W) -- this handles ALL y-range cases free.
    __amdgpu_buffer_rsrc_t rsrc = __builtin_amdgcn_make_buffer_rsrc(
        (void*)img, (short)0, HWc * 4, 0x00020000);
#endif

    float acc = 0.f;

#pragma unroll
    for (int k = 0; k < K * K; ++k) {
        const int ky = k / K - 1;
        const int kx = k % K - 1;

        const float y = (float)(h + ky) + oy[k];
        const float x = (float)(w + kx) + ox[k];

        const float y0f = floorf(y);
        const float x0f = floorf(x);
        const float ly = y - y0f, lx = x - x0f;
        const int y0 = (int)y0f, x0 = (int)x0f;

        float v00, v01, v10, v11;

#if USE_BUF
        // One address computation; other corners are immediate offsets.
        const int fb = (y0 << 9) + x0;            // flat element index (may be negative)
        const int fbB = fb * 4;                   // byte voffset; unsigned wrap == exact mod-2^32
        v00 = __uint_as_float(__builtin_amdgcn_raw_buffer_load_b32(rsrc, fbB,            0, 0));
        v01 = __uint_as_float(__builtin_amdgcn_raw_buffer_load_b32(rsrc, fbB + 4,        0, 0));
        v10 = __uint_as_float(__builtin_amdgcn_raw_buffer_load_b32(rsrc, fbB + Wc*4,     0, 0));
        v11 = __uint_as_float(__builtin_amdgcn_raw_buffer_load_b32(rsrc, fbB + Wc*4 + 4, 0, 0));
        // x-range masks (the only aliasing the buffer bounds check can't see).
        const bool vx0 = (unsigned)x0       < (unsigned)Wc;
        const bool vx1 = (unsigned)(x0 + 1) < (unsigned)Wc;
        v00 = vx0 ? v00 : 0.f;   v10 = vx0 ? v10 : 0.f;
        v01 = vx1 ? v01 : 0.f;   v11 = vx1 ? v11 : 0.f;
#else
        const int y1 = y0 + 1, x1 = x0 + 1;
        auto corner = [&](int yi, int xi) -> float {
            const bool valid = ((unsigned)yi < (unsigned)Hc) & ((unsigned)xi < (unsigned)Wc);
            return valid ? img[yi * Wc + xi] : 0.f;
        };
        v00 = corner(y0, x0); v01 = corner(y0, x1);
        v10 = corner(y1, x0); v11 = corner(y1, x1);
#endif

        // lerp form: 7 FMA-class ops instead of 12
        const float top = v00 + lx * (v01 - v00);
        const float bot = v10 + lx * (v11 - v10);
        acc += wgt[k] * (top + ly * (bot - top));   // wgt[k]: wave-uniform s_load
    }

    out[p] = acc;
}

extern "C" void kernel_launch(void* const* d_in, const int* in_sizes, int n_in,
                              void* d_out, int out_size, void* d_ws, size_t ws_size,
                              hipStream_t stream)
{
    const float* inp = (const float*)d_in[0];   // (8,512,512)
    const float* wgt = (const float*)d_in[1];   // (1,1,3,3) = 9 floats
    const float* off = (const float*)d_in[2];   // (8,18,512,512)
    float* out = (float*)d_out;

    const int npix  = Bc * HWc;
    const int block = 256;
    const int grid  = npix / block;

    deform_conv2d_kernel<<<grid, block, 0, stream>>>(inp, wgt, off, out);
}

// Round 5
// 35.846 us; speedup vs baseline: 1.7025x; 1.1145x over previous
//
#include <hip/hip_runtime.h>

constexpr int K  = 3;
constexpr int Hc = 512, Wc = 512, Bc = 8;
constexpr int HWc = Hc * Wc;

__device__ __forceinline__ float bload(__amdgpu_buffer_rsrc_t r, int vo, int so) {
    return __uint_as_float(__builtin_amdgcn_raw_buffer_load_b32(r, vo, so, 0));
}

// load 4 consecutive window floats at byte offset (fbB + RB), apply column masks
#define LOADROW(V0, V1, V2, V3, RB)                                  \
    V0 = bload(irsrc, fbB + (RB),      0);                           \
    V1 = bload(irsrc, fbB + (RB) + 4,  0);                           \
    V2 = bload(irsrc, fbB + (RB) + 8,  0);                           \
    V3 = bload(irsrc, fbB + (RB) + 12, 0);                           \
    V0 = c0 ? V0 : 0.f; V2 = c2 ? V2 : 0.f; V3 = c3 ? V3 : 0.f;

// 3 taps (kx=-1,0,1) using window rows A (=y0) and B (=y1), k = KB..KB+2
#define TAPROW(A0, A1, A2, A3, B0, B1, B2, B3, KB)                   \
    {                                                                \
        float t, bo;                                                 \
        t  = A0 + ox[KB]     * (A1 - A0);                            \
        bo = B0 + ox[KB]     * (B1 - B0);                            \
        acc += wk[KB]     * (t + oy[KB]     * (bo - t));             \
        t  = A1 + ox[KB + 1] * (A2 - A1);                            \
        bo = B1 + ox[KB + 1] * (B2 - B1);                            \
        acc += wk[KB + 1] * (t + oy[KB + 1] * (bo - t));             \
        t  = A2 + ox[KB + 2] * (A3 - A2);                            \
        bo = B2 + ox[KB + 2] * (B3 - B2);                            \
        acc += wk[KB + 2] * (t + oy[KB + 2] * (bo - t));             \
    }

__global__ __launch_bounds__(256, 8) void deform_conv2d_kernel(
    const float* __restrict__ inp,     // (B,H,W)
    const float* __restrict__ wgt,     // (K*K)
    const float* __restrict__ off,     // (B, 2*K*K, H, W)
    float* __restrict__ out)           // (B,H,W)
{
    const int p  = blockIdx.x * blockDim.x + threadIdx.x;   // one pixel per thread
    const int b  = p >> 18;            // / (512*512)
    const int hw = p & (HWc - 1);
    const int h  = hw >> 9;
    const int w  = hw & (Wc - 1);

    // SRD over this batch's 18 offset planes: one voffset, plane via scalar soffset
    __amdgpu_buffer_rsrc_t orsrc = __builtin_amdgcn_make_buffer_rsrc(
        (void*)(off + (size_t)b * (2 * K * K) * HWc), (short)0,
        (2 * K * K) * HWc * 4, 0x00020000);
    // SRD over this batch's image plane: bounds check zeroes row-OOB taps for free
    __amdgpu_buffer_rsrc_t irsrc = __builtin_amdgcn_make_buffer_rsrc(
        (void*)(inp + (size_t)b * HWc), (short)0, HWc * 4, 0x00020000);

    const int hwB = hw * 4;

    float oy[K * K], ox[K * K];
#pragma unroll
    for (int k = 0; k < K * K; ++k) {
        oy[k] = bload(orsrc, hwB, (2 * k)     * HWc * 4);
        ox[k] = bload(orsrc, hwB, (2 * k + 1) * HWc * 4);
    }

    float mn = fminf(oy[0], ox[0]);
    float mx = fmaxf(oy[0], ox[0]);
#pragma unroll
    for (int k = 1; k < K * K; ++k) {
        mn = fminf(mn, fminf(oy[k], ox[k]));
        mx = fmaxf(mx, fmaxf(oy[k], ox[k]));
    }

    float wk[K * K];
#pragma unroll
    for (int k = 0; k < K * K; ++k) wk[k] = wgt[k];   // wave-uniform s_loads

    float acc = 0.f;

    if (__all((mn >= 0.f) & (mx < 1.f))) {
        // FAST PATH (wave-uniform): every tap's corner is (h+ky, w+kx).
        // All 9 bilinear taps read a shared 4x4 window: rows h-1..h+2, cols w-1..w+2.
        // ly = oy[k], lx = ox[k] exactly.
        const int  fbB = ((h - 1) * Wc + (w - 1)) * 4;  // window(0,0) byte offset; may wrap (OOB->0)
        const bool c0 = (w >= 1);        // col w-1
        const bool c2 = (w <= Wc - 2);   // col w+1
        const bool c3 = (w <= Wc - 3);   // col w+2

        float a0, a1, a2, a3, b0, b1, b2, b3;
        LOADROW(a0, a1, a2, a3, 0)            // image row h-1
        LOADROW(b0, b1, b2, b3, Wc * 4)       // image row h
        TAPROW(a0, a1, a2, a3, b0, b1, b2, b3, 0)   // ky=-1
        LOADROW(a0, a1, a2, a3, 2 * Wc * 4)   // image row h+1 (reuse regs)
        TAPROW(b0, b1, b2, b3, a0, a1, a2, a3, 3)   // ky=0
        LOADROW(b0, b1, b2, b3, 3 * Wc * 4)   // image row h+2
        TAPROW(a0, a1, a2, a3, b0, b1, b2, b3, 6)   // ky=1
    } else {
        // GENERAL PATH: correct for arbitrary offsets (round-4 structure)
#pragma unroll
        for (int k = 0; k < K * K; ++k) {
            const int ky = k / K - 1;
            const int kx = k % K - 1;

            const float y = (float)(h + ky) + oy[k];
            const float x = (float)(w + kx) + ox[k];

            const float y0f = floorf(y);
            const float x0f = floorf(x);
            const float ly = y - y0f, lx = x - x0f;
            const int y0 = (int)y0f, x0 = (int)x0f;

            const int fbB = ((y0 << 9) + x0) * 4;
            float v00 = bload(irsrc, fbB,              0);
            float v01 = bload(irsrc, fbB + 4,          0);
            float v10 = bload(irsrc, fbB + Wc * 4,     0);
            float v11 = bload(irsrc, fbB + Wc * 4 + 4, 0);
            const bool vx0 = (unsigned)x0       < (unsigned)Wc;
            const bool vx1 = (unsigned)(x0 + 1) < (unsigned)Wc;
            v00 = vx0 ? v00 : 0.f;   v10 = vx0 ? v10 : 0.f;
            v01 = vx1 ? v01 : 0.f;   v11 = vx1 ? v11 : 0.f;

            const float top = v00 + lx * (v01 - v00);
            const float bot = v10 + lx * (v11 - v10);
            acc += wk[k] * (top + ly * (bot - top));
        }
    }

    out[p] = acc;
}

extern "C" void kernel_launch(void* const* d_in, const int* in_sizes, int n_in,
                              void* d_out, int out_size, void* d_ws, size_t ws_size,
                              hipStream_t stream)
{
    const float* inp = (const float*)d_in[0];   // (8,512,512)
    const float* wgt = (const float*)d_in[1];   // (1,1,3,3) = 9 floats
    const float* off = (const float*)d_in[2];   // (8,18,512,512)
    float* out = (float*)d_out;

    const int npix  = Bc * HWc;
    const int block = 256;
    const int grid  = npix / block;

    deform_conv2d_kernel<<<grid, block, 0, stream>>>(inp, wgt, off, out);
}

// Round 6
// 33.194 us; speedup vs baseline: 1.8386x; 1.0799x over previous
//
#include <hip/hip_runtime.h>

constexpr int K  = 3;
constexpr int Hc = 512, Wc = 512, Bc = 8;
constexpr int HWc = Hc * Wc;

typedef __attribute__((ext_vector_type(2))) unsigned int u32x2;
typedef __attribute__((ext_vector_type(4))) unsigned int u32x4;

__device__ __forceinline__ float bl32(__amdgpu_buffer_rsrc_t r, int vo, int so) {
    return __uint_as_float(__builtin_amdgcn_raw_buffer_load_b32(r, vo, so, 0));
}
__device__ __forceinline__ u32x2 bl64(__amdgpu_buffer_rsrc_t r, int vo, int so) {
    return __builtin_amdgcn_raw_buffer_load_b64(r, vo, so, 0);
}
__device__ __forceinline__ u32x4 bl128(__amdgpu_buffer_rsrc_t r, int vo, int so) {
    return __builtin_amdgcn_raw_buffer_load_b128(r, vo, so, 0);
}

__global__ __launch_bounds__(256, 6) void deform_conv2d_kernel(
    const float* __restrict__ inp,     // (B,H,W)
    const float* __restrict__ wgt,     // (K*K)
    const float* __restrict__ off,     // (B, 2*K*K, H, W)
    float* __restrict__ out)           // (B,H,W)
{
    const int idx = blockIdx.x * blockDim.x + threadIdx.x;   // 4 pixels per thread
    const int p4  = idx << 2;
    const int b   = p4 >> 18;            // / (512*512)
    const int hw  = p4 & (HWc - 1);
    const int h   = hw >> 9;
    const int w   = hw & (Wc - 1);       // multiple of 4

    __amdgpu_buffer_rsrc_t orsrc = __builtin_amdgcn_make_buffer_rsrc(
        (void*)(off + (size_t)b * (2 * K * K) * HWc), (short)0,
        (2 * K * K) * HWc * 4, 0x00020000);
    __amdgpu_buffer_rsrc_t irsrc = __builtin_amdgcn_make_buffer_rsrc(
        (void*)(inp + (size_t)b * HWc), (short)0, HWc * 4, 0x00020000);

    float wk[K * K];
#pragma unroll
    for (int k = 0; k < K * K; ++k) wk[k] = wgt[k];   // wave-uniform s_loads

    // ---- shared 4x7 window: rows h-1..h+2, cols w-1..w+5 (zero-padded) ----
    // Row OOB: SRD bounds check returns 0 for the whole row (flat index wraps OOB).
    // Col wrap-aliasing fixed by 3 masks (col w-1 when w==0; cols w+4,w+5 when w==508).
    const int  fbB = ((h - 1) * Wc + (w - 1)) * 4;   // 16B-misaligned by 12
    const bool m0 = (w >= 1);
    const bool m5 = (w + 4 < Wc);
    const bool m6 = (w + 5 < Wc);

    float win[4][7];
#pragma unroll
    for (int r = 0; r < 4; ++r) {
        const int rb = fbB + r * Wc * 4;
        const float e0 = bl32 (irsrc, rb,      0);   // col w-1
        const u32x4 md = bl128(irsrc, rb + 4,  0);   // cols w..w+3 (16B aligned)
        const u32x2 e5 = bl64 (irsrc, rb + 20, 0);   // cols w+4,w+5 (8B aligned)
        win[r][0] = m0 ? e0 : 0.f;
        win[r][1] = __uint_as_float(md.x);
        win[r][2] = __uint_as_float(md.y);
        win[r][3] = __uint_as_float(md.z);
        win[r][4] = __uint_as_float(md.w);
        win[r][5] = m5 ? __uint_as_float(e5.x) : 0.f;
        win[r][6] = m6 ? __uint_as_float(e5.y) : 0.f;
    }

    const int hwB = hw * 4;
    float acc[4] = {0.f, 0.f, 0.f, 0.f};

#pragma unroll
    for (int k = 0; k < K * K; ++k) {
        const int ky = k / K - 1;
        const int kx = k % K - 1;

        const u32x4 oyu = bl128(orsrc, hwB, (2 * k)     * HWc * 4);
        const u32x4 oxu = bl128(orsrc, hwB, (2 * k + 1) * HWc * 4);
        const float oya[4] = {__uint_as_float(oyu.x), __uint_as_float(oyu.y),
                              __uint_as_float(oyu.z), __uint_as_float(oyu.w)};
        const float oxa[4] = {__uint_as_float(oxu.x), __uint_as_float(oxu.y),
                              __uint_as_float(oxu.z), __uint_as_float(oxu.w)};

        const float mn = fminf(fminf(fminf(oya[0], oya[1]), fminf(oya[2], oya[3])),
                               fminf(fminf(oxa[0], oxa[1]), fminf(oxa[2], oxa[3])));
        const float mx = fmaxf(fmaxf(fmaxf(oya[0], oya[1]), fmaxf(oya[2], oya[3])),
                               fmaxf(fmaxf(oxa[0], oxa[1]), fmaxf(oxa[2], oxa[3])));

        if (__all((mn >= 0.f) && (mx < 1.f))) {
            // FAST (wave-uniform): floor(y)=h+ky, floor(x)=w+j+kx; ly=oy, lx=ox.
            const int r0 = ky + 1;
#pragma unroll
            for (int j = 0; j < 4; ++j) {
                const int c = j + kx + 1;   // window col of x0; static after unroll
                const float t  = win[r0][c]     + oxa[j] * (win[r0][c + 1]     - win[r0][c]);
                const float bo = win[r0 + 1][c] + oxa[j] * (win[r0 + 1][c + 1] - win[r0 + 1][c]);
                acc[j] += wk[k] * (t + oya[j] * (bo - t));
            }
        } else {
            // GENERAL (never taken for this data; keeps arbitrary-offset correctness)
#pragma unroll
            for (int j = 0; j < 4; ++j) {
                const float y = (float)(h + ky)     + oya[j];
                const float x = (float)(w + j + kx) + oxa[j];
                const float y0f = floorf(y), x0f = floorf(x);
                const float ly = y - y0f,  lx = x - x0f;
                const int y0 = (int)y0f, x0 = (int)x0f;

                const int cb = ((y0 << 9) + x0) * 4;
                float v00 = bl32(irsrc, cb,              0);
                float v01 = bl32(irsrc, cb + 4,          0);
                float v10 = bl32(irsrc, cb + Wc * 4,     0);
                float v11 = bl32(irsrc, cb + Wc * 4 + 4, 0);
                const bool vx0 = (unsigned)x0       < (unsigned)Wc;
                const bool vx1 = (unsigned)(x0 + 1) < (unsigned)Wc;
                v00 = vx0 ? v00 : 0.f;   v10 = vx0 ? v10 : 0.f;
                v01 = vx1 ? v01 : 0.f;   v11 = vx1 ? v11 : 0.f;

                const float top = v00 + lx * (v01 - v00);
                const float bot = v10 + lx * (v11 - v10);
                acc[j] += wk[k] * (top + ly * (bot - top));
            }
        }
    }

    float4 o;
    o.x = acc[0]; o.y = acc[1]; o.z = acc[2]; o.w = acc[3];
    *reinterpret_cast<float4*>(out + p4) = o;    // 16B aligned, coalesced
}

extern "C" void kernel_launch(void* const* d_in, const int* in_sizes, int n_in,
                              void* d_out, int out_size, void* d_ws, size_t ws_size,
                              hipStream_t stream)
{
    const float* inp = (const float*)d_in[0];   // (8,512,512)
    const float* wgt = (const float*)d_in[1];   // (1,1,3,3) = 9 floats
    const float* off = (const float*)d_in[2];   // (8,18,512,512)
    float* out = (float*)d_out;

    const int nthreads = Bc * HWc / 4;          // 4 px per thread
    const int block = 256;
    const int grid  = nthreads / block;         // 2048

    deform_conv2d_kernel<<<grid, block, 0, stream>>>(inp, wgt, off, out);
}